// Round 19
// baseline (81.658 us; speedup 1.0000x reference)
//
#include <hip/hip_runtime.h>
#include <math.h>

#define H_ 128
#define W_ 128
#define C_ 64
#define B_ 8
#define HW 16384          // H_*W_
#define NPIX (B_*HW)      // 131072

typedef __attribute__((ext_vector_type(8))) short short8;
typedef __attribute__((ext_vector_type(4))) float f32x4;

__device__ __forceinline__ float softplus_fast(float v) {
    return fmaxf(v, 0.f) + __logf(1.f + __expf(-fabsf(v)));
}

__device__ __forceinline__ unsigned short f2bf(float f) {
    unsigned u = __builtin_bit_cast(unsigned, f);
    unsigned r = (u + 0x7fffu + ((u >> 16) & 1u)) >> 16;
    return (unsigned short)r;
}

__device__ __forceinline__ float bf_lo(unsigned u) {
    return __builtin_bit_cast(float, u << 16);
}
__device__ __forceinline__ float bf_hi(unsigned u) {
    return __builtin_bit_cast(float, u & 0xffff0000u);
}

// async global->LDS, 16B per lane. LDS dest must be linear: base + lane*16.
__device__ __forceinline__ void gl_lds16(const void* g, void* l) {
    __builtin_amdgcn_global_load_lds(
        (const __attribute__((address_space(1))) void*)g,
        (__attribute__((address_space(3))) void*)l, 16, 0, 0);
}

// K0: (a) w2 -> bf16 A-frags (wtr); (b) w_reduce -> A-frags (wtr1);
//     (c) w_span -> 2 zero-padded A-frags (wtr2); (d) block 0 zeroes
//     stats[128] + zgz[128] (must run every call; stats accumulate).
__global__ __launch_bounds__(256) void k0_wtr(const float* __restrict__ w2,
                                              const float* __restrict__ wr,
                                              const float* __restrict__ wspan,
                                              unsigned short* __restrict__ wtr,
                                              unsigned short* __restrict__ wtr1,
                                              unsigned short* __restrict__ wtr2,
                                              float* __restrict__ stats)
{
    int t = blockIdx.x * 256 + threadIdx.x;
    if (t < 256) stats[t] = 0.f;            // stats[128] + zeros[128]
    if (t < 512) {
        int lane = t & 63, f = t >> 6;
        int mt = f >> 1, kh = f & 1;
        int o  = mt * 16 + (lane & 15);
        int c0 = kh * 32 + ((lane >> 4) << 3);
        uint4 pk;
        unsigned short* pv = (unsigned short*)&pk;
#pragma unroll
        for (int e = 0; e < 8; ++e)
            pv[e] = f2bf(wr[o * C_ + c0 + e]);
        *(uint4*)&wtr1[(size_t)t * 8] = pk;
    } else if (t < 640) {
        int tt = t - 512;
        int lane = tt & 63, kh = tt >> 6;
        int o  = lane & 15;
        int c0 = (kh << 5) + ((lane >> 4) << 3);
        uint4 pk;
        unsigned short* pv = (unsigned short*)&pk;
#pragma unroll
        for (int e = 0; e < 8; ++e)
            pv[e] = (o < 9) ? f2bf(wspan[o * C_ + c0 + e]) : (unsigned short)0;
        *(uint4*)&wtr2[(size_t)tt * 8] = pk;
    }
    if (t >= 4 * 18 * 64) return;
    int lane = t & 63;
    int f    = (t >> 6) % 18;
    int wv   = t / (18 * 64);
    int koff = f >> 1, ch = f & 1;
    int o = wv * 16 + (lane & 15);
    int cb = ch * 32 + ((lane >> 4) << 3);
    uint4 pk;
    unsigned short* pv = (unsigned short*)&pk;
#pragma unroll
    for (int e = 0; e < 8; ++e)
        pv[e] = f2bf(w2[(size_t)o * 576 + (size_t)(cb + e) * 9 + koff]);
    *(uint4*)&wtr[(size_t)t * 8] = pk;
}

// K1: r = W_reduce @ x + b_reduce via MFMA implicit GEMM; BN stats folded in;
// also flushes staged bf16 x (pixel-major) to xq. Unchanged.
__global__ __launch_bounds__(256) void k1_mfma(
    const float* __restrict__ x, const unsigned short* __restrict__ wtr1,
    const float* __restrict__ br, unsigned short* __restrict__ rb,
    unsigned short* __restrict__ xq, float* __restrict__ stats)
{
    __shared__ unsigned short xb[256 * 64];   // 32KB, chunk-XOR swizzled
    __shared__ float brs[C_];
    __shared__ float ls[128];
    int tid = threadIdx.x;
    int blk = blockIdx.x;
    int pid0 = blk << 8;
    int b    = pid0 >> 14;
    int rem0 = pid0 & (HW - 1);
    const float* xbase = x + (((size_t)b * C_) << 14) + rem0;

    if (tid < C_) brs[tid] = br[tid];
    if (tid < 128) ls[tid] = 0.f;

    int p = tid;
#pragma unroll
    for (int m = 0; m < 8; ++m) {
        float tmp[8];
#pragma unroll
        for (int e = 0; e < 8; ++e)
            tmp[e] = xbase[((size_t)(m * 8 + e) << 14) + p];
        unsigned pk[4];
#pragma unroll
        for (int e = 0; e < 4; ++e)
            pk[e] = (unsigned)f2bf(tmp[2 * e]) | ((unsigned)f2bf(tmp[2 * e + 1]) << 16);
        *(uint4*)&xb[(p << 6) + ((m ^ (p & 7)) << 3)] = *(uint4*)pk;
    }

    int wid = tid >> 6, lane = tid & 63;
    int nl  = lane & 15;
    int kg  = lane >> 4;

    short8 af[8];
    const short8* wp = (const short8*)wtr1;
#pragma unroll
    for (int f = 0; f < 8; ++f) af[f] = wp[f * 64 + lane];

    f32x4 acc[4][4];
#pragma unroll
    for (int mt = 0; mt < 4; ++mt)
#pragma unroll
        for (int nt = 0; nt < 4; ++nt) acc[mt][nt] = (f32x4){0.f, 0.f, 0.f, 0.f};

    __syncthreads();

    int nbase = wid << 6;
#pragma unroll
    for (int nt = 0; nt < 4; ++nt) {
        int pp = nbase + (nt << 4) + nl;
#pragma unroll
        for (int kh = 0; kh < 2; ++kh) {
            int m = kh * 4 + kg;
            short8 bf = *(const short8*)&xb[(pp << 6) + ((m ^ (pp & 7)) << 3)];
#pragma unroll
            for (int mt = 0; mt < 4; ++mt)
                acc[mt][nt] = __builtin_amdgcn_mfma_f32_16x16x32_bf16(
                    af[mt * 2 + kh], bf, acc[mt][nt], 0, 0, 0);
        }
    }

    // xq flush: own row of xb still holds bf16 x; contiguous 128B store.
    {
        uint4* xp = (uint4*)(xq + ((size_t)(pid0 + p) << 6));
#pragma unroll
        for (int m = 0; m < 8; ++m)
            xp[m] = *(const uint4*)&xb[(p << 6) + ((m ^ (p & 7)) << 3)];
    }

    __syncthreads();

    float s_[16], q_[16];
#pragma unroll
    for (int i = 0; i < 16; ++i) { s_[i] = 0.f; q_[i] = 0.f; }

#pragma unroll
    for (int mt = 0; mt < 4; ++mt) {
        int c = (mt << 4) + (kg << 2);
        float b0 = brs[c], b1 = brs[c + 1], b2v = brs[c + 2], b3 = brs[c + 3];
        int chunk = c >> 3;
#pragma unroll
        for (int nt = 0; nt < 4; ++nt) {
            int pp = nbase + (nt << 4) + nl;
            f32x4 a = acc[mt][nt];
            float v0 = a[0] + b0, v1 = a[1] + b1, v2 = a[2] + b2v, v3 = a[3] + b3;
            s_[mt * 4 + 0] += v0; q_[mt * 4 + 0] += v0 * v0;
            s_[mt * 4 + 1] += v1; q_[mt * 4 + 1] += v1 * v1;
            s_[mt * 4 + 2] += v2; q_[mt * 4 + 2] += v2 * v2;
            s_[mt * 4 + 3] += v3; q_[mt * 4 + 3] += v3 * v3;
            unsigned lo = (unsigned)f2bf(v0) | ((unsigned)f2bf(v1) << 16);
            unsigned hi = (unsigned)f2bf(v2) | ((unsigned)f2bf(v3) << 16);
            unsigned* dst = (unsigned*)&xb[(pp << 6) + ((chunk ^ (pp & 7)) << 3) + ((kg & 1) << 2)];
            dst[0] = lo;
            dst[1] = hi;
        }
    }

#pragma unroll
    for (int i = 0; i < 16; ++i) {
#pragma unroll
        for (int m = 1; m <= 8; m <<= 1) {
            s_[i] += __shfl_xor(s_[i], m, 64);
            q_[i] += __shfl_xor(q_[i], m, 64);
        }
    }
    if (nl == 0) {
#pragma unroll
        for (int i = 0; i < 16; ++i) {
            int c = ((i >> 2) << 4) + (kg << 2) + (i & 3);
            atomicAdd(&ls[c], s_[i]);
            atomicAdd(&ls[64 + c], q_[i]);
        }
    }
    __syncthreads();
    if (tid < 128) atomicAdd(&stats[tid], ls[tid]);

    uint4* rp = (uint4*)(rb + ((size_t)(pid0 + p) << 6));
#pragma unroll
    for (int m = 0; m < 8; ++m)
        rp[m] = *(const uint4*)&xb[(p << 6) + ((m ^ (p & 7)) << 3)];
}

// K34 v8: identical to v7 except XCD-aware block remap — 512 blocks on 8
// XCDs; remap=(blk&7)*64+(blk>>3) is bijective and gives each XCD one full
// batch-image (64 adjacent tiles): halo reads become L2 hits, adjacent
// tiles' 64B half-line out-writes merge in the same XCD's L2.
__global__ __launch_bounds__(512, 4) void k34_fused(
    const unsigned short* __restrict__ xq, const unsigned short* __restrict__ rb,
    const float* __restrict__ stats, const float* __restrict__ gamma,
    const float* __restrict__ beta, const unsigned short* __restrict__ wtr2,
    const float* __restrict__ bspan, const unsigned short* __restrict__ wtr,
    const float* __restrict__ b2, float* __restrict__ out)
{
    __shared__ unsigned short xh[400 * 64];   // 51.2KB: [pixel q][slot s]·8ch
    __shared__ unsigned short zt[324 * 32];   // 20.7KB (kl overlays)
    __shared__ float a_s[C_], c_s[C_];

    int tid = threadIdx.x;
    if (tid < C_) {
        float inv_n = 1.f / (float)NPIX;
        float mu  = stats[tid] * inv_n;
        float var = stats[C_ + tid] * inv_n - mu * mu;
        float is  = rsqrtf(var + 1e-5f);
        float a   = gamma[tid] * is;
        a_s[tid] = a;
        c_s[tid] = beta[tid] - mu * a;
    }

    // XCD-aware bijective remap (512 = 8 XCDs x 64 tiles)
    int blk   = blockIdx.x;
    int remap = ((blk & 7) << 6) + (blk >> 3);
    int b = remap >> 6, t = remap & 63;
    int h0 = (t >> 3) << 4, w0 = (t & 7) << 4;
    const unsigned short* xqb = xq + (((size_t)b) << 20);  // b * HW * 64
    const unsigned short* zgz = (const unsigned short*)(stats + 128);

    // ---- single-burst halo stage: 3200 items, slot (q,s) <- chunk s^(q&7)
    // (pre-swizzled global source; LDS dest linear) ----
#pragma unroll
    for (int k = 0; k < 7; ++k) {
        int item = (k << 9) + tid;
        if (k < 6 || item < 3200) {
            int q  = item >> 3;
            int s  = item & 7;
            int hr = q / 20, hc = q - hr * 20;
            int gh = h0 + hr - 2, gw = w0 + hc - 2;
            const unsigned short* src = zgz;
            if ((unsigned)gh < 128u && (unsigned)gw < 128u)
                src = xqb + (((size_t)((gh << 7) + gw)) << 6) + ((s ^ (q & 7)) << 3);
            gl_lds16(src, xh + (item << 3));
        }
    }

    int lane = tid & 63;
    int w_  = tid >> 6;            // wave 0..7
    int nl  = lane & 15;
    int kg  = lane >> 4;
    short8 af0 = ((const short8*)wtr2)[lane];
    short8 af1 = ((const short8*)wtr2)[64 + lane];

    // ---- kern for 324(336) halo pixels via MFMA (DMA flies underneath) ----
    float aa[2][8], cc[2][8];
    __syncthreads();               // a_s/c_s ready (DMA still in flight)
#pragma unroll
    for (int kh = 0; kh < 2; ++kh) {
        int cb = (kh << 5) + (kg << 3);
#pragma unroll
        for (int e = 0; e < 8; ++e) { aa[kh][e] = a_s[cb + e]; cc[kh][e] = c_s[cb + e]; }
    }

    float* kl = (float*)zt;        // kern bounce, 11.7KB of zt
#pragma unroll
    for (int i3 = 0; i3 < 3; ++i3) {
        int col = w_ * 3 + i3;
        if (col < 21) {
            int hp = (col << 4) + nl;
            int py = hp / 18, px = hp - py * 18;
            int gh = h0 + py - 1, gw = w0 + px - 1;
            int ghc = min(max(gh, 0), 127), gwc = min(max(gw, 0), 127);
            int pid2 = (b << 14) + (ghc << 7) + gwc;
            f32x4 acc9 = (f32x4){0.f, 0.f, 0.f, 0.f};
#pragma unroll
            for (int kh = 0; kh < 2; ++kh) {
                uint4 rv = *(const uint4*)(rb + ((size_t)pid2 << 6) + (kh << 5) + (kg << 3));
                const unsigned* ru = (const unsigned*)&rv;
                unsigned po[4];
#pragma unroll
                for (int e2 = 0; e2 < 4; ++e2) {
                    float lo = bf_lo(ru[e2]);
                    float hi = bf_hi(ru[e2]);
                    float r0 = fmaxf(aa[kh][2 * e2]     * lo + cc[kh][2 * e2],     0.f);
                    float r1 = fmaxf(aa[kh][2 * e2 + 1] * hi + cc[kh][2 * e2 + 1], 0.f);
                    po[e2] = (unsigned)f2bf(r0) | ((unsigned)f2bf(r1) << 16);
                }
                short8 bfrag = __builtin_bit_cast(short8, *(uint4*)po);
                acc9 = __builtin_amdgcn_mfma_f32_16x16x32_bf16(
                    kh ? af1 : af0, bfrag, acc9, 0, 0, 0);
            }
#pragma unroll
            for (int e = 0; e < 4; ++e) {
                int rr = (kg << 2) + e;
                if (rr < 9) kl[hp * 9 + rr] = acc9[e];
            }
        }
    }
    __syncthreads();

    bool hasPix = tid < 324;
    float kern0[9];
    if (hasPix) {
#pragma unroll
        for (int k = 0; k < 9; ++k) kern0[k] = kl[tid * 9 + k] + bspan[k];
    }
    __syncthreads();               // kl reads done; DMA drained (halo ready)

    int py0 = tid / 18, px0 = tid - py0 * 18;
    bool ib0 = hasPix && ((unsigned)(h0 + py0 - 1) < 128u) && ((unsigned)(w0 + px0 - 1) < 128u);
    int hbase = py0 * 20 + px0;    // halo pixel idx of tap (0,0)

    // z for one 8-ch group g -> zt chunk g&3 (barrier-free: xh is complete)
    auto computeZ = [&](int g) {
        if (hasPix) {
            unsigned pk[4];
            if (ib0) {
                float az[8];
#pragma unroll
                for (int e = 0; e < 8; ++e) az[e] = 0.f;
#pragma unroll
                for (int i = 0; i < 3; ++i)
#pragma unroll
                    for (int j = 0; j < 3; ++j) {
                        int q = hbase + i * 20 + j;
                        uint4 tv = *(const uint4*)&xh[(q << 6) + ((g ^ (q & 7)) << 3)];
                        const unsigned* tu = (const unsigned*)&tv;
                        float kv = kern0[i * 3 + j];
#pragma unroll
                        for (int e2 = 0; e2 < 4; ++e2) {
                            az[2 * e2]     += kv * bf_lo(tu[e2]);
                            az[2 * e2 + 1] += kv * bf_hi(tu[e2]);
                        }
                    }
#pragma unroll
                for (int cp = 0; cp < 4; ++cp)
                    pk[cp] = (unsigned)f2bf(softplus_fast(az[2 * cp]))
                           | ((unsigned)f2bf(softplus_fast(az[2 * cp + 1])) << 16);
            } else {
#pragma unroll
                for (int cp = 0; cp < 4; ++cp) pk[cp] = 0u;
            }
            *(uint4*)&zt[(tid << 5) + (((g & 3) ^ ((tid >> 1) & 3)) << 3)] = *(uint4*)pk;
        }
    };

    // ---- conv: wave owns (og, yh); acc persists across the two kh passes ----
    int og = w_ & 3, yh = w_ >> 2;
    int ybase = yh << 3;
    f32x4 acc[8];
#pragma unroll
    for (int nt = 0; nt < 8; ++nt) acc[nt] = (f32x4){0.f, 0.f, 0.f, 0.f};

    const short8* wp = (const short8*)wtr;
    auto convHalf = [&](int kh) {
        short8 wfh[9];
#pragma unroll
        for (int f9 = 0; f9 < 9; ++f9)
            wfh[f9] = wp[(size_t)(og * 18 + f9 * 2 + kh) * 64 + lane];
#pragma unroll
        for (int yy = 0; yy < 10; ++yy) {
            int y = ybase + yy;
            short8 bf[3];
#pragma unroll
            for (int j = 0; j < 3; ++j) {
                int p = y * 18 + j + nl;
                bf[j] = *(const short8*)&zt[(p << 5) + ((kg ^ ((p >> 1) & 3)) << 3)];
            }
#pragma unroll
            for (int i = 0; i < 3; ++i) {
                int nt = yy - i;
                if (nt >= 0 && nt < 8) {
#pragma unroll
                    for (int j = 0; j < 3; ++j)
                        acc[nt] = __builtin_amdgcn_mfma_f32_16x16x32_bf16(
                            wfh[i * 3 + j], bf[j], acc[nt], 0, 0, 0);
                }
            }
        }
    };

    // ---- phase A: z ch0-31 (groups 0-3, no internal barriers), conv kh=0 ----
    computeZ(0); computeZ(1); computeZ(2); computeZ(3);
    __syncthreads();
    convHalf(0);
    __syncthreads();               // zt reads done before zB overwrites

    // ---- phase B: z ch32-63 (groups 4-7), conv kh=1 ----
    computeZ(4); computeZ(5); computeZ(6); computeZ(7);
    __syncthreads();
    convHalf(1);

    float bias[4];
#pragma unroll
    for (int r = 0; r < 4; ++r) bias[r] = b2[(og << 4) + (kg << 2) + r];

    size_t ob = ((size_t)b) << 20;
#pragma unroll
    for (int nt = 0; nt < 8; ++nt) {
        int h = h0 + ybase + nt;
#pragma unroll
        for (int r = 0; r < 4; ++r) {
            int o = (og << 4) + (kg << 2) + r;
            float v = acc[nt][r] + bias[r];
            out[ob + ((size_t)o << 14) + (h << 7) + w0 + nl] = softplus_fast(v);
        }
    }
}

extern "C" void kernel_launch(void* const* d_in, const int* in_sizes, int n_in,
                              void* d_out, int out_size, void* d_ws, size_t ws_size,
                              hipStream_t stream)
{
    const float* x   = (const float*)d_in[0];
    const float* wr  = (const float*)d_in[1];
    const float* br  = (const float*)d_in[2];
    const float* gam = (const float*)d_in[3];
    const float* bet = (const float*)d_in[4];
    const float* wsp = (const float*)d_in[5];
    const float* bsp = (const float*)d_in[6];
    const float* w2  = (const float*)d_in[7];
    const float* b2  = (const float*)d_in[8];
    float* out = (float*)d_out;

    // ws: rb bf16[NPIX*64] | xq bf16[NPIX*64] | wtr[4608*8] | wtr1[512*8]
    //     | wtr2[128*8] | stats f32[128] | zeros f32[128]   (~33.64 MB)
    unsigned short* rb   = (unsigned short*)d_ws;
    unsigned short* xq   = rb + (size_t)NPIX * C_;
    unsigned short* wtr  = xq + (size_t)NPIX * C_;
    unsigned short* wtr1 = wtr + 4608 * 8;
    unsigned short* wtr2 = wtr1 + 512 * 8;
    float* stats = (float*)(wtr2 + 128 * 8);

    k0_wtr<<<18, 256, 0, stream>>>(w2, wr, wsp, wtr, wtr1, wtr2, stats);
    k1_mfma<<<NPIX / 256, 256, 0, stream>>>(x, wtr1, br, rb, xq, stats);
    k34_fused<<<NPIX / 256, 512, 0, stream>>>(xq, rb, stats, gam, bet, wtr2, bsp,
                                              wtr, b2, out);
}

// Round 20
// 77.462 us; speedup vs baseline: 1.0542x; 1.0542x over previous
//
#include <hip/hip_runtime.h>
#include <math.h>

#define H_ 128
#define W_ 128
#define C_ 64
#define B_ 8
#define HW 16384          // H_*W_
#define NPIX (B_*HW)      // 131072

typedef __attribute__((ext_vector_type(8))) short short8;
typedef __attribute__((ext_vector_type(4))) float f32x4;

__device__ __forceinline__ float softplus_fast(float v) {
    return fmaxf(v, 0.f) + __logf(1.f + __expf(-fabsf(v)));
}

__device__ __forceinline__ unsigned short f2bf(float f) {
    unsigned u = __builtin_bit_cast(unsigned, f);
    unsigned r = (u + 0x7fffu + ((u >> 16) & 1u)) >> 16;
    return (unsigned short)r;
}

__device__ __forceinline__ float bf_lo(unsigned u) {
    return __builtin_bit_cast(float, u << 16);
}
__device__ __forceinline__ float bf_hi(unsigned u) {
    return __builtin_bit_cast(float, u & 0xffff0000u);
}

// async global->LDS, 16B per lane. LDS dest must be linear: base + lane*16.
__device__ __forceinline__ void gl_lds16(const void* g, void* l) {
    __builtin_amdgcn_global_load_lds(
        (const __attribute__((address_space(1))) void*)g,
        (__attribute__((address_space(3))) void*)l, 16, 0, 0);
}

// K0: (a) w2 -> bf16 A-frags (wtr); (b) w_reduce -> A-frags (wtr1);
//     (c) w_span -> 2 zero-padded A-frags (wtr2); (d) block 0 zeroes
//     stats[128] + zgz[128] (must run every call; stats accumulate).
__global__ __launch_bounds__(256) void k0_wtr(const float* __restrict__ w2,
                                              const float* __restrict__ wr,
                                              const float* __restrict__ wspan,
                                              unsigned short* __restrict__ wtr,
                                              unsigned short* __restrict__ wtr1,
                                              unsigned short* __restrict__ wtr2,
                                              float* __restrict__ stats)
{
    int t = blockIdx.x * 256 + threadIdx.x;
    if (t < 256) stats[t] = 0.f;            // stats[128] + zeros[128]
    if (t < 512) {
        int lane = t & 63, f = t >> 6;
        int mt = f >> 1, kh = f & 1;
        int o  = mt * 16 + (lane & 15);
        int c0 = kh * 32 + ((lane >> 4) << 3);
        uint4 pk;
        unsigned short* pv = (unsigned short*)&pk;
#pragma unroll
        for (int e = 0; e < 8; ++e)
            pv[e] = f2bf(wr[o * C_ + c0 + e]);
        *(uint4*)&wtr1[(size_t)t * 8] = pk;
    } else if (t < 640) {
        int tt = t - 512;
        int lane = tt & 63, kh = tt >> 6;
        int o  = lane & 15;
        int c0 = (kh << 5) + ((lane >> 4) << 3);
        uint4 pk;
        unsigned short* pv = (unsigned short*)&pk;
#pragma unroll
        for (int e = 0; e < 8; ++e)
            pv[e] = (o < 9) ? f2bf(wspan[o * C_ + c0 + e]) : (unsigned short)0;
        *(uint4*)&wtr2[(size_t)tt * 8] = pk;
    }
    if (t >= 4 * 18 * 64) return;
    int lane = t & 63;
    int f    = (t >> 6) % 18;
    int wv   = t / (18 * 64);
    int koff = f >> 1, ch = f & 1;
    int o = wv * 16 + (lane & 15);
    int cb = ch * 32 + ((lane >> 4) << 3);
    uint4 pk;
    unsigned short* pv = (unsigned short*)&pk;
#pragma unroll
    for (int e = 0; e < 8; ++e)
        pv[e] = f2bf(w2[(size_t)o * 576 + (size_t)(cb + e) * 9 + koff]);
    *(uint4*)&wtr[(size_t)t * 8] = pk;
}

// K1: r = W_reduce @ x + b_reduce via MFMA implicit GEMM; BN stats folded in;
// also flushes staged bf16 x (pixel-major) to xq. Unchanged.
__global__ __launch_bounds__(256) void k1_mfma(
    const float* __restrict__ x, const unsigned short* __restrict__ wtr1,
    const float* __restrict__ br, unsigned short* __restrict__ rb,
    unsigned short* __restrict__ xq, float* __restrict__ stats)
{
    __shared__ unsigned short xb[256 * 64];   // 32KB, chunk-XOR swizzled
    __shared__ float brs[C_];
    __shared__ float ls[128];
    int tid = threadIdx.x;
    int blk = blockIdx.x;
    int pid0 = blk << 8;
    int b    = pid0 >> 14;
    int rem0 = pid0 & (HW - 1);
    const float* xbase = x + (((size_t)b * C_) << 14) + rem0;

    if (tid < C_) brs[tid] = br[tid];
    if (tid < 128) ls[tid] = 0.f;

    int p = tid;
#pragma unroll
    for (int m = 0; m < 8; ++m) {
        float tmp[8];
#pragma unroll
        for (int e = 0; e < 8; ++e)
            tmp[e] = xbase[((size_t)(m * 8 + e) << 14) + p];
        unsigned pk[4];
#pragma unroll
        for (int e = 0; e < 4; ++e)
            pk[e] = (unsigned)f2bf(tmp[2 * e]) | ((unsigned)f2bf(tmp[2 * e + 1]) << 16);
        *(uint4*)&xb[(p << 6) + ((m ^ (p & 7)) << 3)] = *(uint4*)pk;
    }

    int wid = tid >> 6, lane = tid & 63;
    int nl  = lane & 15;
    int kg  = lane >> 4;

    short8 af[8];
    const short8* wp = (const short8*)wtr1;
#pragma unroll
    for (int f = 0; f < 8; ++f) af[f] = wp[f * 64 + lane];

    f32x4 acc[4][4];
#pragma unroll
    for (int mt = 0; mt < 4; ++mt)
#pragma unroll
        for (int nt = 0; nt < 4; ++nt) acc[mt][nt] = (f32x4){0.f, 0.f, 0.f, 0.f};

    __syncthreads();

    int nbase = wid << 6;
#pragma unroll
    for (int nt = 0; nt < 4; ++nt) {
        int pp = nbase + (nt << 4) + nl;
#pragma unroll
        for (int kh = 0; kh < 2; ++kh) {
            int m = kh * 4 + kg;
            short8 bf = *(const short8*)&xb[(pp << 6) + ((m ^ (pp & 7)) << 3)];
#pragma unroll
            for (int mt = 0; mt < 4; ++mt)
                acc[mt][nt] = __builtin_amdgcn_mfma_f32_16x16x32_bf16(
                    af[mt * 2 + kh], bf, acc[mt][nt], 0, 0, 0);
        }
    }

    // xq flush: own row of xb still holds bf16 x; contiguous 128B store.
    {
        uint4* xp = (uint4*)(xq + ((size_t)(pid0 + p) << 6));
#pragma unroll
        for (int m = 0; m < 8; ++m)
            xp[m] = *(const uint4*)&xb[(p << 6) + ((m ^ (p & 7)) << 3)];
    }

    __syncthreads();

    float s_[16], q_[16];
#pragma unroll
    for (int i = 0; i < 16; ++i) { s_[i] = 0.f; q_[i] = 0.f; }

#pragma unroll
    for (int mt = 0; mt < 4; ++mt) {
        int c = (mt << 4) + (kg << 2);
        float b0 = brs[c], b1 = brs[c + 1], b2v = brs[c + 2], b3 = brs[c + 3];
        int chunk = c >> 3;
#pragma unroll
        for (int nt = 0; nt < 4; ++nt) {
            int pp = nbase + (nt << 4) + nl;
            f32x4 a = acc[mt][nt];
            float v0 = a[0] + b0, v1 = a[1] + b1, v2 = a[2] + b2v, v3 = a[3] + b3;
            s_[mt * 4 + 0] += v0; q_[mt * 4 + 0] += v0 * v0;
            s_[mt * 4 + 1] += v1; q_[mt * 4 + 1] += v1 * v1;
            s_[mt * 4 + 2] += v2; q_[mt * 4 + 2] += v2 * v2;
            s_[mt * 4 + 3] += v3; q_[mt * 4 + 3] += v3 * v3;
            unsigned lo = (unsigned)f2bf(v0) | ((unsigned)f2bf(v1) << 16);
            unsigned hi = (unsigned)f2bf(v2) | ((unsigned)f2bf(v3) << 16);
            unsigned* dst = (unsigned*)&xb[(pp << 6) + ((chunk ^ (pp & 7)) << 3) + ((kg & 1) << 2)];
            dst[0] = lo;
            dst[1] = hi;
        }
    }

#pragma unroll
    for (int i = 0; i < 16; ++i) {
#pragma unroll
        for (int m = 1; m <= 8; m <<= 1) {
            s_[i] += __shfl_xor(s_[i], m, 64);
            q_[i] += __shfl_xor(q_[i], m, 64);
        }
    }
    if (nl == 0) {
#pragma unroll
        for (int i = 0; i < 16; ++i) {
            int c = ((i >> 2) << 4) + (kg << 2) + (i & 3);
            atomicAdd(&ls[c], s_[i]);
            atomicAdd(&ls[64 + c], q_[i]);
        }
    }
    __syncthreads();
    if (tid < 128) atomicAdd(&stats[tid], ls[tid]);

    uint4* rp = (uint4*)(rb + ((size_t)(pid0 + p) << 6));
#pragma unroll
    for (int m = 0; m < 8; ++m)
        rp[m] = *(const uint4*)&xb[(p << 6) + ((m ^ (p & 7)) << 3)];
}

// K34 v9: v8 + flattened z-phase. z work = flat (pixel,group) items over all
// 512 threads (no 324-thread guard); kern re-packed bf16 into a dedicated
// 7.8KB LDS array (stride 6 dwords) so any thread can process any pixel.
// LDS 80.2KB -> still 2 blocks/CU. Staging/kern-MFMA/conv unchanged.
__global__ __launch_bounds__(512, 4) void k34_fused(
    const unsigned short* __restrict__ xq, const unsigned short* __restrict__ rb,
    const float* __restrict__ stats, const float* __restrict__ gamma,
    const float* __restrict__ beta, const unsigned short* __restrict__ wtr2,
    const float* __restrict__ bspan, const unsigned short* __restrict__ wtr,
    const float* __restrict__ b2, float* __restrict__ out)
{
    __shared__ unsigned short xh[400 * 64];   // 51,200B: [pixel q][slot s]·8ch
    __shared__ unsigned short zt[324 * 32];   // 20,736B (kl overlays)
    __shared__ unsigned kern_l[324 * 6];      // 7,776B bf16 kern (9 used of 12)
    __shared__ float a_s[C_], c_s[C_];

    int tid = threadIdx.x;
    if (tid < C_) {
        float inv_n = 1.f / (float)NPIX;
        float mu  = stats[tid] * inv_n;
        float var = stats[C_ + tid] * inv_n - mu * mu;
        float is  = rsqrtf(var + 1e-5f);
        float a   = gamma[tid] * is;
        a_s[tid] = a;
        c_s[tid] = beta[tid] - mu * a;
    }

    // XCD-aware bijective remap (512 = 8 XCDs x 64 tiles)
    int blk   = blockIdx.x;
    int remap = ((blk & 7) << 6) + (blk >> 3);
    int b = remap >> 6, t = remap & 63;
    int h0 = (t >> 3) << 4, w0 = (t & 7) << 4;
    const unsigned short* xqb = xq + (((size_t)b) << 20);  // b * HW * 64
    const unsigned short* zgz = (const unsigned short*)(stats + 128);

    // ---- single-burst halo stage: 3200 items, slot (q,s) <- chunk s^(q&7) ----
#pragma unroll
    for (int k = 0; k < 7; ++k) {
        int item = (k << 9) + tid;
        if (k < 6 || item < 3200) {
            int q  = item >> 3;
            int s  = item & 7;
            int hr = q / 20, hc = q - hr * 20;
            int gh = h0 + hr - 2, gw = w0 + hc - 2;
            const unsigned short* src = zgz;
            if ((unsigned)gh < 128u && (unsigned)gw < 128u)
                src = xqb + (((size_t)((gh << 7) + gw)) << 6) + ((s ^ (q & 7)) << 3);
            gl_lds16(src, xh + (item << 3));
        }
    }

    int lane = tid & 63;
    int w_  = tid >> 6;            // wave 0..7
    int nl  = lane & 15;
    int kg  = lane >> 4;
    short8 af0 = ((const short8*)wtr2)[lane];
    short8 af1 = ((const short8*)wtr2)[64 + lane];

    // ---- kern for 324(336) halo pixels via MFMA (DMA flies underneath) ----
    float aa[2][8], cc[2][8];
    __syncthreads();               // a_s/c_s ready (DMA still in flight)
#pragma unroll
    for (int kh = 0; kh < 2; ++kh) {
        int cb = (kh << 5) + (kg << 3);
#pragma unroll
        for (int e = 0; e < 8; ++e) { aa[kh][e] = a_s[cb + e]; cc[kh][e] = c_s[cb + e]; }
    }

    float* kl = (float*)zt;        // kern bounce, 11.7KB of zt
#pragma unroll
    for (int i3 = 0; i3 < 3; ++i3) {
        int col = w_ * 3 + i3;
        if (col < 21) {
            int hp = (col << 4) + nl;
            int py = hp / 18, px = hp - py * 18;
            int gh = h0 + py - 1, gw = w0 + px - 1;
            int ghc = min(max(gh, 0), 127), gwc = min(max(gw, 0), 127);
            int pid2 = (b << 14) + (ghc << 7) + gwc;
            f32x4 acc9 = (f32x4){0.f, 0.f, 0.f, 0.f};
#pragma unroll
            for (int kh = 0; kh < 2; ++kh) {
                uint4 rv = *(const uint4*)(rb + ((size_t)pid2 << 6) + (kh << 5) + (kg << 3));
                const unsigned* ru = (const unsigned*)&rv;
                unsigned po[4];
#pragma unroll
                for (int e2 = 0; e2 < 4; ++e2) {
                    float lo = bf_lo(ru[e2]);
                    float hi = bf_hi(ru[e2]);
                    float r0 = fmaxf(aa[kh][2 * e2]     * lo + cc[kh][2 * e2],     0.f);
                    float r1 = fmaxf(aa[kh][2 * e2 + 1] * hi + cc[kh][2 * e2 + 1], 0.f);
                    po[e2] = (unsigned)f2bf(r0) | ((unsigned)f2bf(r1) << 16);
                }
                short8 bfrag = __builtin_bit_cast(short8, *(uint4*)po);
                acc9 = __builtin_amdgcn_mfma_f32_16x16x32_bf16(
                    kh ? af1 : af0, bfrag, acc9, 0, 0, 0);
            }
#pragma unroll
            for (int e = 0; e < 4; ++e) {
                int rr = (kg << 2) + e;
                if (rr < 9) kl[hp * 9 + rr] = acc9[e];
            }
        }
    }
    __syncthreads();

    // kern: kl(f32) + bspan -> bf16-packed kern_l (stride 6 dwords)
    if (tid < 324) {
        float kern0[9];
#pragma unroll
        for (int k = 0; k < 9; ++k) kern0[k] = kl[tid * 9 + k] + bspan[k];
        unsigned kp0 = (unsigned)f2bf(kern0[0]) | ((unsigned)f2bf(kern0[1]) << 16);
        unsigned kp1 = (unsigned)f2bf(kern0[2]) | ((unsigned)f2bf(kern0[3]) << 16);
        unsigned kp2 = (unsigned)f2bf(kern0[4]) | ((unsigned)f2bf(kern0[5]) << 16);
        unsigned kp3 = (unsigned)f2bf(kern0[6]) | ((unsigned)f2bf(kern0[7]) << 16);
        unsigned kp4 = (unsigned)f2bf(kern0[8]);
        *(uint2*)&kern_l[tid * 6]     = make_uint2(kp0, kp1);
        *(uint2*)&kern_l[tid * 6 + 2] = make_uint2(kp2, kp3);
        kern_l[tid * 6 + 4] = kp4;
    }
    __syncthreads();               // kern_l ready; kl reads done; DMA drained

    // z-phase: flat (pixel, group) items over ALL 512 threads.
    // phase 0 -> groups 0-3, phase 1 -> groups 4-7; 1296 items each.
    auto zPhase = [&](int phase) {
#pragma unroll 1
        for (int k = 0; k < 3; ++k) {
            int item = (k << 9) + tid;
            if (item < 1296) {
                int g4  = item / 324;
                int pix = item - g4 * 324;
                int g   = (phase << 2) + g4;
                int py  = pix / 18, px = pix - py * 18;
                bool ib = ((unsigned)(h0 + py - 1) < 128u) &&
                          ((unsigned)(w0 + px - 1) < 128u);
                unsigned pk[4];
                if (ib) {
                    uint2 ka  = *(const uint2*)&kern_l[pix * 6];
                    uint2 kb2 = *(const uint2*)&kern_l[pix * 6 + 2];
                    unsigned kc = kern_l[pix * 6 + 4];
                    float kn[9];
                    kn[0] = bf_lo(ka.x);  kn[1] = bf_hi(ka.x);
                    kn[2] = bf_lo(ka.y);  kn[3] = bf_hi(ka.y);
                    kn[4] = bf_lo(kb2.x); kn[5] = bf_hi(kb2.x);
                    kn[6] = bf_lo(kb2.y); kn[7] = bf_hi(kb2.y);
                    kn[8] = bf_lo(kc);
                    int hb = py * 20 + px;
                    float az[8];
#pragma unroll
                    for (int e = 0; e < 8; ++e) az[e] = 0.f;
#pragma unroll
                    for (int i = 0; i < 3; ++i)
#pragma unroll
                        for (int j = 0; j < 3; ++j) {
                            int q = hb + i * 20 + j;
                            uint4 tv = *(const uint4*)&xh[(q << 6) + ((g ^ (q & 7)) << 3)];
                            const unsigned* tu = (const unsigned*)&tv;
                            float kv = kn[i * 3 + j];
#pragma unroll
                            for (int e2 = 0; e2 < 4; ++e2) {
                                az[2 * e2]     += kv * bf_lo(tu[e2]);
                                az[2 * e2 + 1] += kv * bf_hi(tu[e2]);
                            }
                        }
#pragma unroll
                    for (int cp = 0; cp < 4; ++cp)
                        pk[cp] = (unsigned)f2bf(softplus_fast(az[2 * cp]))
                               | ((unsigned)f2bf(softplus_fast(az[2 * cp + 1])) << 16);
                } else {
#pragma unroll
                    for (int cp = 0; cp < 4; ++cp) pk[cp] = 0u;
                }
                *(uint4*)&zt[(pix << 5) + (((g & 3) ^ ((pix >> 1) & 3)) << 3)] = *(uint4*)pk;
            }
        }
    };

    // ---- conv: wave owns (og, yh); acc persists across the two kh passes ----
    int og = w_ & 3, yh = w_ >> 2;
    int ybase = yh << 3;
    f32x4 acc[8];
#pragma unroll
    for (int nt = 0; nt < 8; ++nt) acc[nt] = (f32x4){0.f, 0.f, 0.f, 0.f};

    const short8* wp = (const short8*)wtr;
    auto convHalf = [&](int kh) {
        short8 wfh[9];
#pragma unroll
        for (int f9 = 0; f9 < 9; ++f9)
            wfh[f9] = wp[(size_t)(og * 18 + f9 * 2 + kh) * 64 + lane];
#pragma unroll
        for (int yy = 0; yy < 10; ++yy) {
            int y = ybase + yy;
            short8 bf[3];
#pragma unroll
            for (int j = 0; j < 3; ++j) {
                int p = y * 18 + j + nl;
                bf[j] = *(const short8*)&zt[(p << 5) + ((kg ^ ((p >> 1) & 3)) << 3)];
            }
#pragma unroll
            for (int i = 0; i < 3; ++i) {
                int nt = yy - i;
                if (nt >= 0 && nt < 8) {
#pragma unroll
                    for (int j = 0; j < 3; ++j)
                        acc[nt] = __builtin_amdgcn_mfma_f32_16x16x32_bf16(
                            wfh[i * 3 + j], bf[j], acc[nt], 0, 0, 0);
                }
            }
        }
    };

    // ---- phase A: z ch0-31 (flat), conv kh=0 ----
    zPhase(0);
    __syncthreads();
    convHalf(0);
    __syncthreads();               // zt reads done before zB overwrites

    // ---- phase B: z ch32-63 (flat), conv kh=1 ----
    zPhase(1);
    __syncthreads();
    convHalf(1);

    float bias[4];
#pragma unroll
    for (int r = 0; r < 4; ++r) bias[r] = b2[(og << 4) + (kg << 2) + r];

    size_t ob = ((size_t)b) << 20;
#pragma unroll
    for (int nt = 0; nt < 8; ++nt) {
        int h = h0 + ybase + nt;
#pragma unroll
        for (int r = 0; r < 4; ++r) {
            int o = (og << 4) + (kg << 2) + r;
            float v = acc[nt][r] + bias[r];
            out[ob + ((size_t)o << 14) + (h << 7) + w0 + nl] = softplus_fast(v);
        }
    }
}

extern "C" void kernel_launch(void* const* d_in, const int* in_sizes, int n_in,
                              void* d_out, int out_size, void* d_ws, size_t ws_size,
                              hipStream_t stream)
{
    const float* x   = (const float*)d_in[0];
    const float* wr  = (const float*)d_in[1];
    const float* br  = (const float*)d_in[2];
    const float* gam = (const float*)d_in[3];
    const float* bet = (const float*)d_in[4];
    const float* wsp = (const float*)d_in[5];
    const float* bsp = (const float*)d_in[6];
    const float* w2  = (const float*)d_in[7];
    const float* b2  = (const float*)d_in[8];
    float* out = (float*)d_out;

    // ws: rb bf16[NPIX*64] | xq bf16[NPIX*64] | wtr[4608*8] | wtr1[512*8]
    //     | wtr2[128*8] | stats f32[128] | zeros f32[128]   (~33.64 MB)
    unsigned short* rb   = (unsigned short*)d_ws;
    unsigned short* xq   = rb + (size_t)NPIX * C_;
    unsigned short* wtr  = xq + (size_t)NPIX * C_;
    unsigned short* wtr1 = wtr + 4608 * 8;
    unsigned short* wtr2 = wtr1 + 512 * 8;
    float* stats = (float*)(wtr2 + 128 * 8);

    k0_wtr<<<18, 256, 0, stream>>>(w2, wr, wsp, wtr, wtr1, wtr2, stats);
    k1_mfma<<<NPIX / 256, 256, 0, stream>>>(x, wtr1, br, rb, xq, stats);
    k34_fused<<<NPIX / 256, 512, 0, stream>>>(xq, rb, stats, gam, bet, wtr2, bsp,
                                              wtr, b2, out);
}